// Round 6
// baseline (418.836 us; speedup 1.0000x reference)
//
#include <hip/hip_runtime.h>

// ---------------------------------------------------------------------------
// SparseConvUNet forward, round 6: 4-way k-split + 2-stage software-pipelined
// MFMA convs (32 vox x 32 co block tile, 8 waves), sentinel zero rows,
// fused BN stats (x8 replica f64 atomics), gather-only BN apply.
// ---------------------------------------------------------------------------

typedef short bf16x8 __attribute__((ext_vector_type(8)));
typedef float f32x4 __attribute__((ext_vector_type(4)));
typedef unsigned short ushort_t;

constexpr int D1 = 48, DIM2 = 24, DIM3 = 12;
constexpr int N1 = D1 * D1 * D1;        // 110592
constexpr int N2 = DIM2 * DIM2 * DIM2;  // 13824
constexpr int N3 = DIM3 * DIM3 * DIM3;  // 1728

// ---- workspace layout (float offsets) ----
constexpr size_t OFF_A      = 0;               // x0; idb1; t1 (in-place res)
constexpr size_t OFF_R1     = 3538944;         // b1a_raw; h1_raw
constexpr size_t OFF_CAT1   = 7077888;         // XP overlay; then x1|u1 (N1*64)
constexpr size_t OFF_D1R    = 14155776;        // d1_raw; idb2 (N2*64)
constexpr size_t OFF_R3     = 15040512;        // b2a_raw; h2_raw; t2_raw
constexpr size_t OFF_CAT2   = 15925248;        // x2|u2 (N2*128)
constexpr size_t OFF_D2R    = 17694720;        // N3*96
constexpr size_t OFF_R4     = 17860608;        // N3*96
constexpr size_t OFF_X3R    = 18026496;        // N3*96
// bf16 dense-zeroed buffers, each padded with >=1 sentinel zero row
constexpr size_t OFF_BN1_32 = 18192384;        // (N1*32+128) us
constexpr size_t OFF_BN1_64 = 19961920;        // (N1*64+128) us
constexpr size_t OFF_BN2_64 = 23500928;        // (N2*64+128) us
constexpr size_t OFF_BN2_128= 23943360;        // (N2*128+128) us
constexpr size_t OFF_BN3_96 = 24828160;        // (N3*96+128) us
constexpr size_t OFF_BFEND  = 24911168;        // zeroed region end
constexpr size_t OFF_WT     = 24911168;        // bf16 weights (1,445,888 us)
constexpr size_t OFF_STATS  = 25634112;        // 15 slots * 8 reps * 256 doubles
constexpr size_t STATS_FLOATS = 15 * 2048 * 2; // 61440
constexpr size_t OFF_CNT    = OFF_STATS + STATS_FLOATS;
constexpr size_t OFF_L1     = OFF_CNT + 16;
constexpr size_t OFF_L2     = OFF_L1 + N1;
constexpr size_t OFF_L3     = OFF_L2 + N2;
constexpr size_t OFF_M1     = OFF_L3 + N3;
constexpr size_t OFF_M2     = OFF_M1 + N1 / 4;
constexpr size_t OFF_M3     = OFF_M2 + N2 / 4;

// bf16 weight starts (ushort units), layout [k][co][cipad], zero-padded taps
// (27-tap jobs padded to 32 taps of zeros; 8-tap jobs exact).
// jobs: w_in b1a b1b d1 b2a b2b d2 b3a b3b t2a t2b t1a t1b u2 u1
constexpr int WTS[16] = {0, 32768, 65536, 98304, 114688, 229376, 344064,
                         393216, 669696, 946176, 1175552, 1290240, 1347584,
                         1380352, 1429504, 1445888};

__device__ inline ushort_t f2bf(float f) {
  union { float f; unsigned u; } x; x.f = f;
  unsigned u = x.u + 0x7FFF + ((x.u >> 16) & 1);
  return (ushort_t)(u >> 16);
}

// ---------------------------------------------------------------------------
// mask / list kernels
// ---------------------------------------------------------------------------
__global__ __launch_bounds__(256) void k_mask1(const float* __restrict__ x,
                                               unsigned char* __restrict__ m,
                                               int* __restrict__ list, int* __restrict__ cnt) {
  int v = blockIdx.x * 256 + threadIdx.x;
  if (v >= N1) return;
  const float* p = x + (size_t)v * 6;
  bool a = (p[0] != 0.f) || (p[1] != 0.f) || (p[2] != 0.f) ||
           (p[3] != 0.f) || (p[4] != 0.f) || (p[5] != 0.f);
  m[v] = a ? 1 : 0;
  if (a) { int pos = atomicAdd(cnt, 1); list[pos] = v; }
}

__global__ __launch_bounds__(256) void k_pool(const unsigned char* __restrict__ mf,
                                              unsigned char* __restrict__ mc,
                                              int* __restrict__ list, int* __restrict__ cnt, int DC) {
  int v = blockIdx.x * 256 + threadIdx.x;
  int n = DC * DC * DC;
  if (v >= n) return;
  int w = v % DC, h = (v / DC) % DC, d = v / (DC * DC);
  int DF = 2 * DC;
  bool a = false;
  for (int i = 0; i < 2; i++)
    for (int j = 0; j < 2; j++)
      for (int k = 0; k < 2; k++)
        a |= (mf[(size_t)(((2 * d + i) * DF + (2 * h + j)) * DF + (2 * w + k))] != 0);
  mc[v] = a ? 1 : 0;
  if (a) { int pos = atomicAdd(cnt, 1); list[pos] = v; }
}

// ---------------------------------------------------------------------------
// weight prep: f32 [k][ci][co] -> bf16 [k][co][cipad], zero for padded taps
// ---------------------------------------------------------------------------
struct WJobs {
  const float* src[15];
  int start[16];
  short cinr[15], cipad[15], cout[15], kk[15];
};

__global__ __launch_bounds__(256) void k_wprep(WJobs jb, ushort_t* __restrict__ wt, int total) {
  int gid = blockIdx.x * 256 + threadIdx.x;
  if (gid >= total) return;
  int j = 0;
#pragma unroll
  for (int jj = 0; jj < 15; jj++)
    if (gid >= jb.start[jj + 1]) j = jj + 1;
  int e = gid - jb.start[j];
  int CIP = jb.cipad[j], CO = jb.cout[j], CIR = jb.cinr[j], KKr = jb.kk[j];
  int ci = e % CIP;
  int co = (e / CIP) % CO;
  int k = e / (CIP * CO);
  float v = (k < KKr && ci < CIR) ? jb.src[j][((size_t)k * CIR + ci) * CO + co] : 0.f;
  wt[gid] = f2bf(v);
}

// x (N1 x 6 f32) -> dense bf16 (N1+4) x 32 (zero-padded ci, zero sentinel rows)
__global__ __launch_bounds__(256) void k_xprep(const float* __restrict__ x, ushort_t* __restrict__ xp) {
  int gid = blockIdx.x * 256 + threadIdx.x;
  if (gid >= (N1 + 4) * 8) return;
  int v = gid >> 3, c = (gid & 7) * 4;
  uint2 o = make_uint2(0u, 0u);
  if (v < N1) {
    ushort_t u[4];
#pragma unroll
    for (int j = 0; j < 4; j++) {
      int ci = c + j;
      float f = (ci < 6) ? x[(size_t)v * 6 + ci] : 0.f;
      u[j] = f2bf(f);
    }
    o.x = (unsigned)u[0] | ((unsigned)u[1] << 16);
    o.y = (unsigned)u[2] | ((unsigned)u[3] << 16);
  }
  *(uint2*)&xp[(size_t)v * 32 + c] = o;
}

// ---------------------------------------------------------------------------
// 4-way k-split, 2-stage pipelined MFMA conv.
// Block: 32 voxels x 32 co (blockIdx.y = co group), 512 threads = 8 waves.
// Wave wv: voxel group vg=wv&1 (16 voxels), k-split ks=wv>>1 (taps
// [ks*TPS, ks*TPS+TPS)), full 32-co (2 acc frags). Software pipeline: tap
// j+1's A/B loads issue before tap j's MFMAs (alternating named reg sets).
// OOB/inactive gathers hit a zero sentinel row; padded taps hit zero weights.
// 4-way LDS reduce; fused BN stats into x8-replicated f64 atomics.
// ---------------------------------------------------------------------------
template <int CIPAD, int COUT, int KK, bool UP>
__global__ __launch_bounds__(512, 2) void k_conv6(
    const ushort_t* __restrict__ in, const ushort_t* __restrict__ wt,
    float* __restrict__ out, int ostride, int ooff,
    const float* __restrict__ res, int rstride,
    double* __restrict__ st,
    const int* __restrict__ list, const int* __restrict__ cnt, int DD) {
  constexpr int KCH = CIPAD / 32;
  constexpr int TPS = (KK + 3) / 4;   // taps per k-split: 27->7, 8->2
  __shared__ float red[8][8][64];
  __shared__ float fin[32][33];
  __shared__ int vidx[32];

  int n = cnt[0];
  int base = blockIdx.x * 32;
  if (base >= n) return;
  int t = threadIdx.x, wv = t >> 6, ln = t & 63;
  int vg = wv & 1, ks = wv >> 1;
  int fr = ln & 15, kg = ln >> 4;
  int coblk = blockIdx.y * 32;
  if (t < 32) vidx[t] = (base + t < n) ? list[base + t] : -1;

  int ai = base + vg * 16 + fr;
  int av = (ai < n) ? list[ai] : -1;
  int vv = av < 0 ? 0 : av;
  int ad = vv / (DD * DD), ah = (vv / DD) % DD, aw = vv % DD;
  int pidx = 0, corner = 0;
  if (UP) {
    int DC = DD / 2;
    pidx = (((ad >> 1) * DC) + (ah >> 1)) * DC + (aw >> 1);
    corner = ((ad & 1) << 2) | ((ah & 1) << 1) | (aw & 1);
  }
  const int GDI = UP ? (DD >> 1) : ((KK == 8) ? 2 * DD : DD);  // input grid dim
  const int SENT = GDI * GDI * GDI;                            // zero sentinel row

  int k0 = ks * TPS;

  // gather row index for tap k (clamped); sentinel when invalid
  auto nixOf = [&](int k) -> int {
    int kc = (k < KK) ? k : KK - 1;
    if (UP) {
      return (av >= 0 && corner == kc) ? pidx : SENT;
    } else if (KK == 27) {
      int kd = kc / 9 - 1, kh = (kc / 3) % 3 - 1, kw = kc % 3 - 1;
      int nd = ad + kd, nh = ah + kh, nw = aw + kw;
      bool inb = (av >= 0) && (unsigned)nd < (unsigned)DD &&
                 (unsigned)nh < (unsigned)DD && (unsigned)nw < (unsigned)DD;
      return inb ? (nd * DD + nh) * DD + nw : SENT;
    } else {
      return (av >= 0) ? ((2 * ad + ((kc >> 2) & 1)) * GDI + (2 * ah + ((kc >> 1) & 1))) * GDI +
                             (2 * aw + (kc & 1))
                       : SENT;
    }
  };

  f32x4 acc0 = (f32x4){0.f, 0.f, 0.f, 0.f};
  f32x4 acc1 = (f32x4){0.f, 0.f, 0.f, 0.f};

  bf16x8 aX[KCH], bX[2 * KCH], aY[KCH], bY[2 * KCH];

#define LOADSET(AR, BR, J)                                                         \
  {                                                                                \
    int kk_ = k0 + (J);                                                            \
    int nix_ = nixOf(kk_);                                                         \
    const ushort_t* ap_ = in + (size_t)nix_ * CIPAD + kg * 8;                      \
    _Pragma("unroll") for (int c = 0; c < KCH; c++)                                \
        AR[c] = *(const bf16x8*)(ap_ + c * 32);                                    \
    const ushort_t* wb_ = wt + ((size_t)(kk_ * COUT + coblk + fr)) * CIPAD + kg * 8; \
    _Pragma("unroll") for (int c = 0; c < KCH; c++) {                              \
      BR[c] = *(const bf16x8*)(wb_ + c * 32);                                      \
      BR[KCH + c] = *(const bf16x8*)(wb_ + (size_t)16 * CIPAD + c * 32);           \
    }                                                                              \
  }
#define MFMASET(AR, BR)                                                            \
  _Pragma("unroll") for (int c = 0; c < KCH; c++) {                                \
    acc0 = __builtin_amdgcn_mfma_f32_16x16x32_bf16(AR[c], BR[c], acc0, 0, 0, 0);   \
    acc1 = __builtin_amdgcn_mfma_f32_16x16x32_bf16(AR[c], BR[KCH + c], acc1, 0, 0, 0); \
  }

  LOADSET(aX, bX, 0);
#pragma unroll
  for (int j = 0; j < TPS; j += 2) {
    if (j + 1 < TPS) LOADSET(aY, bY, j + 1);
    MFMASET(aX, bX);
    if (j + 2 < TPS) LOADSET(aX, bX, j + 2);
    if (j + 1 < TPS) MFMASET(aY, bY);
  }
#undef LOADSET
#undef MFMASET

#pragma unroll
  for (int r = 0; r < 4; r++) {
    red[wv][r][ln] = acc0[r];
    red[wv][4 + r][ln] = acc1[r];
  }
  __syncthreads();
#pragma unroll
  for (int e0 = 0; e0 < 2; e0++) {
    int e = t + e0 * 512;
    int ln2 = e & 63, r = (e >> 6) & 3, f = (e >> 8) & 1, vg2 = e >> 9;
    int ei = f * 4 + r;
    float s = red[vg2][ei][ln2] + red[2 + vg2][ei][ln2] +
              red[4 + vg2][ei][ln2] + red[6 + vg2][ei][ln2];
    int fr2 = ln2 & 15, kg2 = ln2 >> 4;
    int slot = vg2 * 16 + kg2 * 4 + r;
    int co = f * 16 + fr2;
    int v = vidx[slot];
    float val = 0.f;
    if (v >= 0) {
      int gco = coblk + co;
      val = s;
      if (res) val += res[(size_t)v * rstride + gco];
      out[(size_t)v * ostride + ooff + gco] = val;
    }
    fin[slot][co] = val;
  }
  __syncthreads();
  if (t < 32) {
    float sm = 0.f, sq = 0.f;
#pragma unroll
    for (int p = 0; p < 32; p++) {
      float x = fin[p][t];
      sm += x; sq += x * x;
    }
    double* sr = st + (size_t)(blockIdx.x & 7) * 256;
    atomicAdd(&sr[coblk + t], (double)sm);
    atomicAdd(&sr[128 + coblk + t], (double)sq);
  }
}

// ---------------------------------------------------------------------------
// BN apply (gather) with per-block finalize prologue (sum 8 replicas).
// Channels c < csplit use slot sA else sB. Output dense-zeroed bf16.
// ---------------------------------------------------------------------------
template <int C>
__global__ __launch_bounds__(256) void k_bnapply2(
    const float* __restrict__ x, int xstr,
    const double* __restrict__ sA, const double* __restrict__ sB, int csplit,
    const int* __restrict__ list, const int* __restrict__ cnt,
    ushort_t* __restrict__ out) {
  __shared__ float mu_s[C], inv_s[C];
  int n = cnt[0];
  int t = threadIdx.x;
  if (t < C) {
    const double* s = (t < csplit) ? (sA + t) : (sB + (t - csplit));
    double sm = 0.0, sq = 0.0;
#pragma unroll
    for (int r = 0; r < 8; r++) { sm += s[r * 256]; sq += s[r * 256 + 128]; }
    double mu = sm / n;
    double var = sq / n - mu * mu;
    mu_s[t] = (float)mu;
    inv_s[t] = rsqrtf((float)fmax(var, 0.0) + 1e-4f);
  }
  __syncthreads();
  int total = n * (C / 4);
  for (int gid = blockIdx.x * 256 + t; gid < total; gid += gridDim.x * 256) {
    int i = gid / (C / 4);
    int c = (gid % (C / 4)) * 4;
    int v = list[i];
    float4 xv = *(const float4*)&x[(size_t)v * xstr + c];
    float xa[4] = {xv.x, xv.y, xv.z, xv.w};
    ushort_t u[4];
#pragma unroll
    for (int j = 0; j < 4; j++)
      u[j] = f2bf(fmaxf((xa[j] - mu_s[c + j]) * inv_s[c + j], 0.f));
    uint2 o; o.x = (unsigned)u[0] | ((unsigned)u[1] << 16);
    o.y = (unsigned)u[2] | ((unsigned)u[3] << 16);
    *(uint2*)&out[(size_t)v * C + c] = o;
  }
}

// final BN apply -> dense f32 d_out (zeros at inactive), replica finalize
__global__ __launch_bounds__(256) void k_bnout(const float* __restrict__ x,
                                               const unsigned char* __restrict__ m,
                                               const double* __restrict__ s,
                                               const int* __restrict__ cnt,
                                               float* __restrict__ out) {
  __shared__ float mu_s[32], inv_s[32];
  int t = threadIdx.x;
  int n = cnt[0];
  if (t < 32) {
    double sm = 0.0, sq = 0.0;
#pragma unroll
    for (int r = 0; r < 8; r++) { sm += s[r * 256 + t]; sq += s[r * 256 + 128 + t]; }
    double mu = sm / n;
    double var = sq / n - mu * mu;
    mu_s[t] = (float)mu;
    inv_s[t] = rsqrtf((float)fmax(var, 0.0) + 1e-4f);
  }
  __syncthreads();
  int gid = blockIdx.x * 256 + t;
  if (gid >= N1 * 8) return;
  int v = gid / 8;
  int c = (gid % 8) * 4;
  float4 o = make_float4(0.f, 0.f, 0.f, 0.f);
  if (m[v]) {
    float4 xv = *(const float4*)&x[(size_t)v * 32 + c];
    o.x = fmaxf((xv.x - mu_s[c + 0]) * inv_s[c + 0], 0.f);
    o.y = fmaxf((xv.y - mu_s[c + 1]) * inv_s[c + 1], 0.f);
    o.z = fmaxf((xv.z - mu_s[c + 2]) * inv_s[c + 2], 0.f);
    o.w = fmaxf((xv.w - mu_s[c + 3]) * inv_s[c + 3], 0.f);
  }
  *(float4*)&out[(size_t)v * 32 + c] = o;
}

// 1x1 shortcut: idb[v][o] = sum_c in[v][c] * wsc[o][c]; grid-stride.
template <int CI, int CO>
__global__ __launch_bounds__(256) void k_sc(const float* __restrict__ in,
                                            const float* __restrict__ wsc,
                                            float* __restrict__ out,
                                            const int* __restrict__ list,
                                            const int* __restrict__ cnt) {
  int n = cnt[0];
  long total = (long)n * CO;
  for (long gid = (long)blockIdx.x * 256 + threadIdx.x; gid < total; gid += (long)gridDim.x * 256) {
    int i = (int)(gid / CO), o = (int)(gid % CO);
    int v = list[i];
    const float4* xr = (const float4*)(in + (size_t)v * CI);
    const float4* wr = (const float4*)(wsc + (size_t)o * CI);
    float a = 0.f;
    for (int c = 0; c < CI / 4; c++) {
      float4 x4 = xr[c], w4 = wr[c];
      a += x4.x * w4.x + x4.y * w4.y + x4.z * w4.z + x4.w * w4.w;
    }
    out[(size_t)v * CO + o] = a;
  }
}

// ---------------------------------------------------------------------------
// host launch
// ---------------------------------------------------------------------------
extern "C" void kernel_launch(void* const* d_in, const int* in_sizes, int n_in,
                              void* d_out, int out_size, void* d_ws, size_t ws_size,
                              hipStream_t stream) {
  float* W = (float*)d_ws;
  const float* x = (const float*)d_in[0];

  float* A    = W + OFF_A;
  float* R1   = W + OFF_R1;
  float* CAT1 = W + OFF_CAT1;
  float* D1R  = W + OFF_D1R;
  float* R3   = W + OFF_R3;
  float* CAT2 = W + OFF_CAT2;
  float* D2R  = W + OFF_D2R;
  float* R4   = W + OFF_R4;
  float* X3R  = W + OFF_X3R;
  ushort_t* XP     = (ushort_t*)(W + OFF_CAT1);  // overlay, dead after x0 conv
  ushort_t* BN1_32 = (ushort_t*)(W + OFF_BN1_32);
  ushort_t* BN1_64 = (ushort_t*)(W + OFF_BN1_64);
  ushort_t* BN2_64 = (ushort_t*)(W + OFF_BN2_64);
  ushort_t* BN2_128= (ushort_t*)(W + OFF_BN2_128);
  ushort_t* BN3_96 = (ushort_t*)(W + OFF_BN3_96);
  ushort_t* WT  = (ushort_t*)(W + OFF_WT);
  double* S0 = (double*)(W + OFF_STATS);
  int* CNT = (int*)(W + OFF_CNT);
  int* L1 = (int*)(W + OFF_L1);
  int* L2 = (int*)(W + OFF_L2);
  int* L3 = (int*)(W + OFF_L3);
  unsigned char* M1 = (unsigned char*)(W + OFF_M1);
  unsigned char* M2 = (unsigned char*)(W + OFF_M2);
  unsigned char* M3 = (unsigned char*)(W + OFF_M3);

  auto S = [&](int i) { return S0 + (size_t)i * 2048; };
  // slots: 0 x0, 1 b1a, 2 x1, 3 d1, 4 b2a, 5 x2, 6 d2, 7 b3a, 8 x3,
  //        9 u2, 10 h2, 11 t2, 12 u1, 13 h1, 14 t1

  hipMemsetAsync(W + OFF_STATS, 0, (STATS_FLOATS + 16) * 4, stream);
  hipMemsetAsync(W + OFF_BN1_32, 0, (OFF_BFEND - OFF_BN1_32) * 4, stream);

  k_mask1<<<N1 / 256, 256, 0, stream>>>(x, M1, L1, CNT + 0);
  k_pool<<<N2 / 256, 256, 0, stream>>>(M1, M2, L2, CNT + 1, DIM2);
  k_pool<<<(N3 + 255) / 256, 256, 0, stream>>>(M2, M3, L3, CNT + 2, DIM3);

  WJobs jb;
  const int srcIdx[15] = {2, 3, 4, 5, 6, 7, 8, 9, 10, 13, 14, 17, 18, 11, 15};
  const short cinr[15]  = {6, 32, 32, 32, 64, 64, 64, 96, 96, 128, 64, 64, 32, 96, 64};
  const short cipad[15] = {32, 32, 32, 32, 64, 64, 64, 96, 96, 128, 64, 64, 32, 96, 64};
  const short couts[15] = {32, 32, 32, 64, 64, 64, 96, 96, 96, 64, 64, 32, 32, 64, 32};
  const short kkr[15]   = {27, 27, 27, 8, 27, 27, 8, 27, 27, 27, 27, 27, 27, 8, 8};
  for (int j = 0; j < 15; j++) {
    jb.src[j] = (const float*)d_in[srcIdx[j]];
    jb.cinr[j] = cinr[j]; jb.cipad[j] = cipad[j]; jb.cout[j] = couts[j];
    jb.kk[j] = kkr[j];
    jb.start[j] = WTS[j];
  }
  jb.start[15] = WTS[15];
  k_wprep<<<(WTS[15] + 255) / 256, 256, 0, stream>>>(jb, WT, WTS[15]);
  k_xprep<<<((N1 + 4) * 8 + 255) / 256, 256, 0, stream>>>(x, XP);

  // grids: 32 voxels per block; covers n1<=16384, n2<=10240, n3=1728
  const int GB1 = 512, GB2 = 320, GB3 = 54;
  const int BNG = 512;

  // ---- level 1 down ----
  k_conv6<32, 32, 27, false><<<dim3(GB1, 1), 512, 0, stream>>>(
      XP, WT + WTS[0], A, 32, 0, nullptr, 0, S(0), L1, CNT + 0, D1);          // x0
  k_bnapply2<32><<<BNG, 256, 0, stream>>>(A, 32, S(0), S(0), 32, L1, CNT + 0, BN1_32);
  k_conv6<32, 32, 27, false><<<dim3(GB1, 1), 512, 0, stream>>>(
      BN1_32, WT + WTS[1], R1, 32, 0, nullptr, 0, S(1), L1, CNT + 0, D1);     // b1a
  k_bnapply2<32><<<BNG, 256, 0, stream>>>(R1, 32, S(1), S(1), 32, L1, CNT + 0, BN1_32);
  k_conv6<32, 32, 27, false><<<dim3(GB1, 1), 512, 0, stream>>>(
      BN1_32, WT + WTS[2], CAT1, 64, 0, A, 32, S(2), L1, CNT + 0, D1);        // x1
  k_bnapply2<32><<<BNG, 256, 0, stream>>>(CAT1, 64, S(2), S(2), 32, L1, CNT + 0, BN1_32);
  k_conv6<32, 64, 8, false><<<dim3(GB2, 2), 512, 0, stream>>>(
      BN1_32, WT + WTS[3], D1R, 64, 0, nullptr, 0, S(3), L2, CNT + 1, DIM2);  // d1

  // ---- level 2 ----
  k_bnapply2<64><<<BNG, 256, 0, stream>>>(D1R, 64, S(3), S(3), 64, L2, CNT + 1, BN2_64);
  k_conv6<64, 64, 27, false><<<dim3(GB2, 2), 512, 0, stream>>>(
      BN2_64, WT + WTS[4], R3, 64, 0, nullptr, 0, S(4), L2, CNT + 1, DIM2);   // b2a
  k_bnapply2<64><<<BNG, 256, 0, stream>>>(R3, 64, S(4), S(4), 64, L2, CNT + 1, BN2_64);
  k_conv6<64, 64, 27, false><<<dim3(GB2, 2), 512, 0, stream>>>(
      BN2_64, WT + WTS[5], CAT2, 128, 0, D1R, 64, S(5), L2, CNT + 1, DIM2);   // x2
  k_bnapply2<64><<<BNG, 256, 0, stream>>>(CAT2, 128, S(5), S(5), 64, L2, CNT + 1, BN2_64);
  k_conv6<64, 96, 8, false><<<dim3(GB3, 3), 512, 0, stream>>>(
      BN2_64, WT + WTS[6], D2R, 96, 0, nullptr, 0, S(6), L3, CNT + 2, DIM3);  // d2

  // ---- level 3 ----
  k_bnapply2<96><<<BNG, 256, 0, stream>>>(D2R, 96, S(6), S(6), 96, L3, CNT + 2, BN3_96);
  k_conv6<96, 96, 27, false><<<dim3(GB3, 3), 512, 0, stream>>>(
      BN3_96, WT + WTS[7], R4, 96, 0, nullptr, 0, S(7), L3, CNT + 2, DIM3);   // b3a
  k_bnapply2<96><<<BNG, 256, 0, stream>>>(R4, 96, S(7), S(7), 96, L3, CNT + 2, BN3_96);
  k_conv6<96, 96, 27, false><<<dim3(GB3, 3), 512, 0, stream>>>(
      BN3_96, WT + WTS[8], X3R, 96, 0, D2R, 96, S(8), L3, CNT + 2, DIM3);     // x3
  k_bnapply2<96><<<BNG, 256, 0, stream>>>(X3R, 96, S(8), S(8), 96, L3, CNT + 2, BN3_96);
  k_conv6<96, 64, 8, true><<<dim3(GB2, 2), 512, 0, stream>>>(
      BN3_96, WT + WTS[13], CAT2, 128, 64, nullptr, 0, S(9), L2, CNT + 1, DIM2);  // u2

  // ---- tail level 2 ----
  k_bnapply2<128><<<BNG, 256, 0, stream>>>(CAT2, 128, S(5), S(9), 64, L2, CNT + 1, BN2_128);
  k_conv6<128, 64, 27, false><<<dim3(GB2, 2), 512, 0, stream>>>(
      BN2_128, WT + WTS[9], R3, 64, 0, nullptr, 0, S(10), L2, CNT + 1, DIM2); // h2
  k_bnapply2<64><<<BNG, 256, 0, stream>>>(R3, 64, S(10), S(10), 64, L2, CNT + 1, BN2_64);
  k_sc<128, 64><<<512, 256, 0, stream>>>(CAT2, (const float*)d_in[12], D1R, L2, CNT + 1);
  k_conv6<64, 64, 27, false><<<dim3(GB2, 2), 512, 0, stream>>>(
      BN2_64, WT + WTS[10], R3, 64, 0, D1R, 64, S(11), L2, CNT + 1, DIM2);    // t2
  k_bnapply2<64><<<BNG, 256, 0, stream>>>(R3, 64, S(11), S(11), 64, L2, CNT + 1, BN2_64);
  k_conv6<64, 32, 8, true><<<dim3(GB1, 1), 512, 0, stream>>>(
      BN2_64, WT + WTS[14], CAT1, 64, 32, nullptr, 0, S(12), L1, CNT + 0, D1);  // u1

  // ---- tail level 1 ----
  k_bnapply2<64><<<BNG, 256, 0, stream>>>(CAT1, 64, S(2), S(12), 32, L1, CNT + 0, BN1_64);
  k_conv6<64, 32, 27, false><<<dim3(GB1, 1), 512, 0, stream>>>(
      BN1_64, WT + WTS[11], R1, 32, 0, nullptr, 0, S(13), L1, CNT + 0, D1);   // h1
  k_bnapply2<32><<<BNG, 256, 0, stream>>>(R1, 32, S(13), S(13), 32, L1, CNT + 0, BN1_32);
  k_sc<64, 32><<<512, 256, 0, stream>>>(CAT1, (const float*)d_in[16], A, L1, CNT + 0);
  k_conv6<32, 32, 27, false><<<dim3(GB1, 1), 512, 0, stream>>>(
      BN1_32, WT + WTS[12], A, 32, 0, A, 32, S(14), L1, CNT + 0, D1);         // t1
  k_bnout<<<N1 * 8 / 256, 256, 0, stream>>>(A, M1, S(14), CNT + 0, (float*)d_out);
}

// Round 7
// 391.632 us; speedup vs baseline: 1.0695x; 1.0695x over previous
//
#include <hip/hip_runtime.h>

// ---------------------------------------------------------------------------
// SparseConvUNet forward, round 7: persistent-block MFMA convs with full
// weight slice staged in LDS (once per block), 4-way k-split waves, direct
// A-gather with 1-deep prefetch, register-accumulated BN stats.
// ---------------------------------------------------------------------------

typedef short bf16x8 __attribute__((ext_vector_type(8)));
typedef float f32x4 __attribute__((ext_vector_type(4)));
typedef unsigned short ushort_t;

constexpr int D1 = 48, DIM2 = 24, DIM3 = 12;
constexpr int N1 = D1 * D1 * D1;        // 110592
constexpr int N2 = DIM2 * DIM2 * DIM2;  // 13824
constexpr int N3 = DIM3 * DIM3 * DIM3;  // 1728

// ---- workspace layout (float offsets) ----
constexpr size_t OFF_A      = 0;               // x0; idb1; t1 (in-place res)
constexpr size_t OFF_R1     = 3538944;         // b1a_raw; h1_raw
constexpr size_t OFF_CAT1   = 7077888;         // XP overlay; then x1|u1 (N1*64)
constexpr size_t OFF_D1R    = 14155776;        // d1_raw; idb2 (N2*64)
constexpr size_t OFF_R3     = 15040512;        // b2a_raw; h2_raw; t2_raw
constexpr size_t OFF_CAT2   = 15925248;        // x2|u2 (N2*128)
constexpr size_t OFF_D2R    = 17694720;        // N3*96
constexpr size_t OFF_R4     = 17860608;        // N3*96
constexpr size_t OFF_X3R    = 18026496;        // N3*96
// bf16 dense-zeroed buffers, each with >=1 zero sentinel row
constexpr size_t OFF_BN1_32 = 18192384;        // (N1*32+128) us = 1769536 fl
constexpr size_t OFF_BN1_64 = 19961920;        // (N1*64+128) us = 3539008 fl
constexpr size_t OFF_BN2_A  = 23500928;        // (N2*64+128) us = 442432 fl
constexpr size_t OFF_BN2_B  = 23943360;        // (N2*64+128) us
constexpr size_t OFF_BN3_96 = 24385792;        // (N3*96+128) us = 83008 fl
constexpr size_t OFF_BFEND  = 24468800;        // zeroed region end
constexpr size_t OFF_WT     = 24468800;        // bf16 weights (1,347,584 us)
constexpr size_t OFF_STATS  = 25142592;        // 16 slots * 8 reps * 256 doubles
constexpr size_t STATS_FLOATS = 16 * 4096;     // 65536
constexpr size_t OFF_CNT    = OFF_STATS + STATS_FLOATS;
constexpr size_t OFF_L1     = OFF_CNT + 16;
constexpr size_t OFF_L2     = OFF_L1 + N1;
constexpr size_t OFF_L3     = OFF_L2 + N2;
constexpr size_t OFF_M1     = OFF_L3 + N3;
constexpr size_t OFF_M2     = OFF_M1 + N1 / 4;
constexpr size_t OFF_M3     = OFF_M2 + N2 / 4;

// bf16 weight starts (ushort units), layout [k][co][cipad], exact taps.
// jobs: 0 w_in, 1 b1a, 2 b1b, 3 d1, 4 b2a, 5 b2b, 6 d2, 7 b3a, 8 b3b,
//       9 t2aA(ci 0:64), 10 t2aB(ci 64:128), 11 t2b, 12 t1a, 13 t1b, 14 u2, 15 u1
constexpr int WTS[17] = {0, 27648, 55296, 82944, 99328, 209920, 320512,
                         369664, 618496, 867328, 977920, 1088512, 1199104,
                         1254400, 1282048, 1331200, 1347584};

__device__ inline ushort_t f2bf(float f) {
  union { float f; unsigned u; } x; x.f = f;
  unsigned u = x.u + 0x7FFF + ((x.u >> 16) & 1);
  return (ushort_t)(u >> 16);
}

// ---------------------------------------------------------------------------
// mask / list kernels
// ---------------------------------------------------------------------------
__global__ __launch_bounds__(256) void k_mask1(const float* __restrict__ x,
                                               unsigned char* __restrict__ m,
                                               int* __restrict__ list, int* __restrict__ cnt) {
  int v = blockIdx.x * 256 + threadIdx.x;
  if (v >= N1) return;
  const float* p = x + (size_t)v * 6;
  bool a = (p[0] != 0.f) || (p[1] != 0.f) || (p[2] != 0.f) ||
           (p[3] != 0.f) || (p[4] != 0.f) || (p[5] != 0.f);
  m[v] = a ? 1 : 0;
  if (a) { int pos = atomicAdd(cnt, 1); list[pos] = v; }
}

__global__ __launch_bounds__(256) void k_pool(const unsigned char* __restrict__ mf,
                                              unsigned char* __restrict__ mc,
                                              int* __restrict__ list, int* __restrict__ cnt, int DC) {
  int v = blockIdx.x * 256 + threadIdx.x;
  int n = DC * DC * DC;
  if (v >= n) return;
  int w = v % DC, h = (v / DC) % DC, d = v / (DC * DC);
  int DF = 2 * DC;
  bool a = false;
  for (int i = 0; i < 2; i++)
    for (int j = 0; j < 2; j++)
      for (int k = 0; k < 2; k++)
        a |= (mf[(size_t)(((2 * d + i) * DF + (2 * h + j)) * DF + (2 * w + k))] != 0);
  mc[v] = a ? 1 : 0;
  if (a) { int pos = atomicAdd(cnt, 1); list[pos] = v; }
}

// ---------------------------------------------------------------------------
// weight prep: f32 [k][ci_total][co] -> bf16 [k][co][cipad] (ci slice via cio)
// ---------------------------------------------------------------------------
struct WJobs {
  const float* src[16];
  int start[17];
  short cirtot[16], cio[16], cipad[16], cout[16];
};

__global__ __launch_bounds__(256) void k_wprep(WJobs jb, ushort_t* __restrict__ wt, int total) {
  int gid = blockIdx.x * 256 + threadIdx.x;
  if (gid >= total) return;
  int j = 0;
#pragma unroll
  for (int jj = 0; jj < 16; jj++)
    if (gid >= jb.start[jj + 1]) j = jj + 1;
  int e = gid - jb.start[j];
  int CIP = jb.cipad[j], CO = jb.cout[j];
  int CIRT = jb.cirtot[j], CIO = jb.cio[j];
  int ci = e % CIP;
  int co = (e / CIP) % CO;
  int k = e / (CIP * CO);
  float v = (ci + CIO < CIRT) ? jb.src[j][((size_t)k * CIRT + CIO + ci) * CO + co] : 0.f;
  wt[gid] = f2bf(v);
}

// x (N1 x 6 f32) -> dense bf16 (N1+4) x 32 (zero-padded ci, zero sentinel rows)
__global__ __launch_bounds__(256) void k_xprep(const float* __restrict__ x, ushort_t* __restrict__ xp) {
  int gid = blockIdx.x * 256 + threadIdx.x;
  if (gid >= (N1 + 4) * 8) return;
  int v = gid >> 3, c = (gid & 7) * 4;
  uint2 o = make_uint2(0u, 0u);
  if (v < N1) {
    ushort_t u[4];
#pragma unroll
    for (int j = 0; j < 4; j++) {
      int ci = c + j;
      float f = (ci < 6) ? x[(size_t)v * 6 + ci] : 0.f;
      u[j] = f2bf(f);
    }
    o.x = (unsigned)u[0] | ((unsigned)u[1] << 16);
    o.y = (unsigned)u[2] | ((unsigned)u[3] << 16);
  }
  *(uint2*)&xp[(size_t)v * 32 + c] = o;
}

// ---------------------------------------------------------------------------
// Persistent-block MFMA conv. Grid: x = tile stride (32 voxels/tile),
// y = co-block (CB channels). Block = 8 waves = 2 voxel-groups x 4 k-splits.
// Full weight slice [KK][CIPAD][CB] staged once in LDS (layout [k][c][co][kg],
// contiguous per ds_read group). A gathered direct from global (sentinel zero
// row for OOB/inactive). Register-accumulated BN stats -> one atomic at end.
// ---------------------------------------------------------------------------
template <int CIPAD, int CB, int KK, int DD, bool UP>
__global__ __launch_bounds__(512, 2) void k_conv7(
    const ushort_t* __restrict__ in, const ushort_t* __restrict__ wt, int cot,
    float* __restrict__ out, int ostride, int ooff,
    const float* __restrict__ res, int rstride,
    double* __restrict__ st,
    const int* __restrict__ list, const int* __restrict__ cnt) {
  constexpr int KCH = CIPAD / 32;
  constexpr int NCO = CB / 16;
  constexpr int TPS = (KK + 3) / 4;          // taps per k-split wave
  constexpr int BUNITS = KK * KCH * CB * 4;  // bf16x8 units in LDS weights
  __shared__ ushort_t blds[BUNITS * 8];
  __shared__ float red[4][2][NCO * 4][64];
  __shared__ float sred0[CB], sred1[CB];
  __shared__ int vidx[32];

  int n = cnt[0];
  int t = threadIdx.x, wv = t >> 6, ln = t & 63;
  int vg = wv & 1, ks = wv >> 1;
  int fr = ln & 15, kg = ln >> 4;
  int coblk = blockIdx.y * CB;

  // ---- stage full weight slice into LDS (once) ----
  for (int e = t; e < BUNITS; e += 512) {
    int kgs = e & 3;
    int co = (e >> 2) % CB;
    int r2 = (e >> 2) / CB;
    int c = r2 % KCH;
    int k = r2 / KCH;
    bf16x8 w = *(const bf16x8*)(wt + ((size_t)k * cot + coblk + co) * CIPAD + c * 32 + kgs * 8);
    *(bf16x8*)(blds + (size_t)e * 8) = w;
  }
  if (t < CB) { sred0[t] = 0.f; sred1[t] = 0.f; }
  __syncthreads();

  float smr = 0.f, sqr = 0.f;
  int myco = ((t >> 8) % NCO) * 16 + (t & 15);

  for (int tile = blockIdx.x; tile * 32 < n; tile += gridDim.x) {
    int base = tile * 32;
    if (t < 32) vidx[t] = (base + t < n) ? list[base + t] : -1;
    __syncthreads();

    // ---- per-wave compute: 16 voxels x CB co x TPS taps ----
    int av = vidx[vg * 16 + fr];
    int vv = av < 0 ? 0 : av;
    int ad = vv / (DD * DD), ah = (vv / DD) % DD, aw = vv % DD;
    int pidx = 0, corner = -1;
    if (UP) {
      constexpr int DC = DD / 2;
      pidx = (((ad >> 1) * DC) + (ah >> 1)) * DC + (aw >> 1);
      corner = ((ad & 1) << 2) | ((ah & 1) << 1) | (aw & 1);
    }
    constexpr int GDI = UP ? (DD / 2) : ((KK == 8) ? 2 * DD : DD);
    constexpr int SENT = GDI * GDI * GDI;  // zero sentinel row

    const int k0 = ks * TPS;
    auto nixOf = [&](int kq) -> int {
      int kc = (kq < KK) ? kq : KK - 1;
      if (UP) {
        return (av >= 0 && corner == kc) ? pidx : SENT;
      } else if (KK == 27) {
        int kd = kc / 9 - 1, kh = (kc / 3) % 3 - 1, kw = kc % 3 - 1;
        int nd = ad + kd, nh = ah + kh, nw = aw + kw;
        bool inb = (av >= 0) && (unsigned)nd < (unsigned)DD &&
                   (unsigned)nh < (unsigned)DD && (unsigned)nw < (unsigned)DD;
        return inb ? (nd * DD + nh) * DD + nw : SENT;
      } else {
        return (av >= 0) ? ((2 * ad + ((kc >> 2) & 1)) * GDI + (2 * ah + ((kc >> 1) & 1))) * GDI +
                               (2 * aw + (kc & 1))
                         : SENT;
      }
    };
    auto loadA = [&](bf16x8* dst, int kq) {
      int nix = nixOf(kq);
      const ushort_t* ap = in + (size_t)nix * CIPAD + kg * 8;
#pragma unroll
      for (int c = 0; c < KCH; c++) dst[c] = *(const bf16x8*)(ap + c * 32);
    };

    f32x4 acc[NCO];
#pragma unroll
    for (int f = 0; f < NCO; f++) acc[f] = (f32x4){0.f, 0.f, 0.f, 0.f};

    bf16x8 aA[KCH], aB[KCH];
    loadA(aA, k0);
#pragma unroll
    for (int j = 0; j < TPS; j++) {
      bf16x8* cur = (j & 1) ? aB : aA;
      bf16x8* nxt = (j & 1) ? aA : aB;
      if (j + 1 < TPS) loadA(nxt, k0 + j + 1);
      if (k0 + j < KK) {
#pragma unroll
        for (int c = 0; c < KCH; c++) {
#pragma unroll
          for (int f = 0; f < NCO; f++) {
            bf16x8 b = *(const bf16x8*)(blds +
                ((((size_t)((k0 + j) * KCH + c) * CB) + f * 16 + fr) * 4 + kg) * 8);
            acc[f] = __builtin_amdgcn_mfma_f32_16x16x32_bf16(cur[c], b, acc[f], 0, 0, 0);
          }
        }
      }
    }

#pragma unroll
    for (int f = 0; f < NCO; f++)
#pragma unroll
      for (int r = 0; r < 4; r++)
        red[ks][vg][f * 4 + r][ln] = acc[f][r];
    __syncthreads();

    // ---- reduce 4 k-splits, write out, accumulate stats ----
#pragma unroll
    for (int e0 = 0; e0 < NCO; e0++) {
      int e = t + e0 * 512;
      int ln2 = e & 63, r = (e >> 6) & 3;
      int f = (e >> 8) % NCO;
      int vg2 = e / (256 * NCO);
      int ei = f * 4 + r;
      float s = red[0][vg2][ei][ln2] + red[1][vg2][ei][ln2] +
                red[2][vg2][ei][ln2] + red[3][vg2][ei][ln2];
      int slot = vg2 * 16 + (ln2 >> 4) * 4 + r;
      int co = f * 16 + (ln2 & 15);
      int v = vidx[slot];
      if (v >= 0) {
        int gco = coblk + co;
        float val = s;
        if (res) val += res[(size_t)v * rstride + gco];
        out[(size_t)v * ostride + ooff + gco] = val;
        smr += val; sqr += val * val;
      }
    }
    __syncthreads();
  }

  // ---- block stats -> LDS reduce -> global f64 atomics ----
  atomicAdd(&sred0[myco], smr);
  atomicAdd(&sred1[myco], sqr);
  __syncthreads();
  if (t < CB) {
    double* sr = st + (size_t)(blockIdx.x & 7) * 256;
    atomicAdd(&sr[coblk + t], (double)sred0[t]);
    atomicAdd(&sr[128 + coblk + t], (double)sred1[t]);
  }
}

// ---------------------------------------------------------------------------
// BN apply (gather) with replica-finalize prologue. Source col offset coff;
// channels c < csplit use slot sA else sB. Output dense-zeroed bf16.
// ---------------------------------------------------------------------------
template <int C>
__global__ __launch_bounds__(256) void k_bnapply2(
    const float* __restrict__ x, int xstr, int coff,
    const double* __restrict__ sA, const double* __restrict__ sB, int csplit,
    const int* __restrict__ list, const int* __restrict__ cnt,
    ushort_t* __restrict__ out) {
  __shared__ float mu_s[C], inv_s[C];
  int n = cnt[0];
  int t = threadIdx.x;
  if (t < C) {
    const double* s = (t < csplit) ? (sA + t) : (sB + (t - csplit));
    double sm = 0.0, sq = 0.0;
#pragma unroll
    for (int r = 0; r < 8; r++) { sm += s[r * 256]; sq += s[r * 256 + 128]; }
    double mu = sm / n;
    double var = sq / n - mu * mu;
    mu_s[t] = (float)mu;
    inv_s[t] = rsqrtf((float)fmax(var, 0.0) + 1e-4f);
  }
  __syncthreads();
  int total = n * (C / 4);
  for (int gid = blockIdx.x * 256 + t; gid < total; gid += gridDim.x * 256) {
    int i = gid / (C / 4);
    int c = (gid % (C / 4)) * 4;
    int v = list[i];
    float4 xv = *(const float4*)&x[(size_t)v * xstr + coff + c];
    float xa[4] = {xv.x, xv.y, xv.z, xv.w};
    ushort_t u[4];
#pragma unroll
    for (int j = 0; j < 4; j++)
      u[j] = f2bf(fmaxf((xa[j] - mu_s[c + j]) * inv_s[c + j], 0.f));
    uint2 o; o.x = (unsigned)u[0] | ((unsigned)u[1] << 16);
    o.y = (unsigned)u[2] | ((unsigned)u[3] << 16);
    *(uint2*)&out[(size_t)v * C + c] = o;
  }
}

// final BN apply -> dense f32 d_out (zeros at inactive), replica finalize
__global__ __launch_bounds__(256) void k_bnout(const float* __restrict__ x,
                                               const unsigned char* __restrict__ m,
                                               const double* __restrict__ s,
                                               const int* __restrict__ cnt,
                                               float* __restrict__ out) {
  __shared__ float mu_s[32], inv_s[32];
  int t = threadIdx.x;
  int n = cnt[0];
  if (t < 32) {
    double sm = 0.0, sq = 0.0;
#pragma unroll
    for (int r = 0; r < 8; r++) { sm += s[r * 256 + t]; sq += s[r * 256 + 128 + t]; }
    double mu = sm / n;
    double var = sq / n - mu * mu;
    mu_s[t] = (float)mu;
    inv_s[t] = rsqrtf((float)fmax(var, 0.0) + 1e-4f);
  }
  __syncthreads();
  int gid = blockIdx.x * 256 + t;
  if (gid >= N1 * 8) return;
  int v = gid / 8;
  int c = (gid % 8) * 4;
  float4 o = make_float4(0.f, 0.f, 0.f, 0.f);
  if (m[v]) {
    float4 xv = *(const float4*)&x[(size_t)v * 32 + c];
    o.x = fmaxf((xv.x - mu_s[c + 0]) * inv_s[c + 0], 0.f);
    o.y = fmaxf((xv.y - mu_s[c + 1]) * inv_s[c + 1], 0.f);
    o.z = fmaxf((xv.z - mu_s[c + 2]) * inv_s[c + 2], 0.f);
    o.w = fmaxf((xv.w - mu_s[c + 3]) * inv_s[c + 3], 0.f);
  }
  *(float4*)&out[(size_t)v * 32 + c] = o;
}

// 1x1 shortcut: idb[v][o] = sum_c in[v][c] * wsc[o][c]; grid-stride.
template <int CI, int CO>
__global__ __launch_bounds__(256) void k_sc(const float* __restrict__ in,
                                            const float* __restrict__ wsc,
                                            float* __restrict__ out,
                                            const int* __restrict__ list,
                                            const int* __restrict__ cnt) {
  int n = cnt[0];
  long total = (long)n * CO;
  for (long gid = (long)blockIdx.x * 256 + threadIdx.x; gid < total; gid += (long)gridDim.x * 256) {
    int i = (int)(gid / CO), o = (int)(gid % CO);
    int v = list[i];
    const float4* xr = (const float4*)(in + (size_t)v * CI);
    const float4* wr = (const float4*)(wsc + (size_t)o * CI);
    float a = 0.f;
    for (int c = 0; c < CI / 4; c++) {
      float4 x4 = xr[c], w4 = wr[c];
      a += x4.x * w4.x + x4.y * w4.y + x4.z * w4.z + x4.w * w4.w;
    }
    out[(size_t)v * CO + o] = a;
  }
}

// ---------------------------------------------------------------------------
// host launch
// ---------------------------------------------------------------------------
extern "C" void kernel_launch(void* const* d_in, const int* in_sizes, int n_in,
                              void* d_out, int out_size, void* d_ws, size_t ws_size,
                              hipStream_t stream) {
  float* W = (float*)d_ws;
  const float* x = (const float*)d_in[0];

  float* A    = W + OFF_A;
  float* R1   = W + OFF_R1;
  float* CAT1 = W + OFF_CAT1;
  float* D1R  = W + OFF_D1R;
  float* R3   = W + OFF_R3;
  float* CAT2 = W + OFF_CAT2;
  float* D2R  = W + OFF_D2R;
  float* R4   = W + OFF_R4;
  float* X3R  = W + OFF_X3R;
  ushort_t* XP     = (ushort_t*)(W + OFF_CAT1);  // overlay, dead after x0 conv
  ushort_t* BN1_32 = (ushort_t*)(W + OFF_BN1_32);
  ushort_t* BN1_64 = (ushort_t*)(W + OFF_BN1_64);
  ushort_t* BN2A   = (ushort_t*)(W + OFF_BN2_A);
  ushort_t* BN2B   = (ushort_t*)(W + OFF_BN2_B);
  ushort_t* BN3_96 = (ushort_t*)(W + OFF_BN3_96);
  ushort_t* WT  = (ushort_t*)(W + OFF_WT);
  double* S0 = (double*)(W + OFF_STATS);
  int* CNT = (int*)(W + OFF_CNT);
  int* L1 = (int*)(W + OFF_L1);
  int* L2 = (int*)(W + OFF_L2);
  int* L3 = (int*)(W + OFF_L3);
  unsigned char* M1 = (unsigned char*)(W + OFF_M1);
  unsigned char* M2 = (unsigned char*)(W + OFF_M2);
  unsigned char* M3 = (unsigned char*)(W + OFF_M3);

  auto S = [&](int i) { return S0 + (size_t)i * 2048; };
  // slots: 0 x0, 1 b1a, 2 x1, 3 d1, 4 b2a, 5 x2, 6 d2, 7 b3a, 8 x3,
  //        9 u2, 10 h2, 11 t2, 12 u1, 13 h1, 14 t1, 15 dummy

  hipMemsetAsync(W + OFF_STATS, 0, (STATS_FLOATS + 16) * 4, stream);
  hipMemsetAsync(W + OFF_BN1_32, 0, (OFF_BFEND - OFF_BN1_32) * 4, stream);

  k_mask1<<<N1 / 256, 256, 0, stream>>>(x, M1, L1, CNT + 0);
  k_pool<<<N2 / 256, 256, 0, stream>>>(M1, M2, L2, CNT + 1, DIM2);
  k_pool<<<(N3 + 255) / 256, 256, 0, stream>>>(M2, M3, L3, CNT + 2, DIM3);

  WJobs jb;
  const int srcIdx[16]  = {2, 3, 4, 5, 6, 7, 8, 9, 10, 13, 13, 14, 17, 18, 11, 15};
  const short cirtot[16]= {6, 32, 32, 32, 64, 64, 64, 96, 96, 128, 128, 64, 64, 32, 96, 64};
  const short cio[16]   = {0, 0, 0, 0, 0, 0, 0, 0, 0, 0, 64, 0, 0, 0, 0, 0};
  const short cipad[16] = {32, 32, 32, 32, 64, 64, 64, 96, 96, 64, 64, 64, 64, 32, 96, 64};
  const short couts[16] = {32, 32, 32, 64, 64, 64, 96, 96, 96, 64, 64, 64, 32, 32, 64, 32};
  for (int j = 0; j < 16; j++) {
    jb.src[j] = (const float*)d_in[srcIdx[j]];
    jb.cirtot[j] = cirtot[j]; jb.cio[j] = cio[j];
    jb.cipad[j] = cipad[j]; jb.cout[j] = couts[j];
    jb.start[j] = WTS[j];
  }
  jb.start[16] = WTS[16];
  k_wprep<<<(WTS[16] + 255) / 256, 256, 0, stream>>>(jb, WT, WTS[16]);
  k_xprep<<<((N1 + 4) * 8 + 255) / 256, 256, 0, stream>>>(x, XP);

  const int BNG = 512;

  // ---- level 1 down ----
  k_conv7<32, 32, 27, D1, false><<<dim3(256, 1), 512, 0, stream>>>(
      XP, WT + WTS[0], 32, A, 32, 0, nullptr, 0, S(0), L1, CNT + 0);            // x0
  k_bnapply2<32><<<BNG, 256, 0, stream>>>(A, 32, 0, S(0), S(0), 32, L1, CNT + 0, BN1_32);
  k_conv7<32, 32, 27, D1, false><<<dim3(256, 1), 512, 0, stream>>>(
      BN1_32, WT + WTS[1], 32, R1, 32, 0, nullptr, 0, S(1), L1, CNT + 0);       // b1a
  k_bnapply2<32><<<BNG, 256, 0, stream>>>(R1, 32, 0, S(1), S(1), 32, L1, CNT + 0, BN1_32);
  k_conv7<32, 32, 27, D1, false><<<dim3(256, 1), 512, 0, stream>>>(
      BN1_32, WT + WTS[2], 32, CAT1, 64, 0, A, 32, S(2), L1, CNT + 0);          // x1
  k_bnapply2<32><<<BNG, 256, 0, stream>>>(CAT1, 64, 0, S(2), S(2), 32, L1, CNT + 0, BN1_32);
  k_conv7<32, 32, 8, DIM2, false><<<dim3(128, 2), 512, 0, stream>>>(
      BN1_32, WT + WTS[3], 64, D1R, 64, 0, nullptr, 0, S(3), L2, CNT + 1);      // d1

  // ---- level 2 ----
  k_bnapply2<64><<<BNG, 256, 0, stream>>>(D1R, 64, 0, S(3), S(3), 64, L2, CNT + 1, BN2A);
  k_conv7<64, 32, 27, DIM2, false><<<dim3(128, 2), 512, 0, stream>>>(
      BN2A, WT + WTS[4], 64, R3, 64, 0, nullptr, 0, S(4), L2, CNT + 1);         // b2a
  k_bnapply2<64><<<BNG, 256, 0, stream>>>(R3, 64, 0, S(4), S(4), 64, L2, CNT + 1, BN2A);
  k_conv7<64, 32, 27, DIM2, false><<<dim3(128, 2), 512, 0, stream>>>(
      BN2A, WT + WTS[5], 64, CAT2, 128, 0, D1R, 64, S(5), L2, CNT + 1);         // x2
  k_bnapply2<64><<<BNG, 256, 0, stream>>>(CAT2, 128, 0, S(5), S(5), 64, L2, CNT + 1, BN2A);
  k_conv7<64, 32, 8, DIM3, false><<<dim3(54, 3), 512, 0, stream>>>(
      BN2A, WT + WTS[6], 96, D2R, 96, 0, nullptr, 0, S(6), L3, CNT + 2);        // d2

  // ---- level 3 ----
  k_bnapply2<96><<<BNG, 256, 0, stream>>>(D2R, 96, 0, S(6), S(6), 96, L3, CNT + 2, BN3_96);
  k_conv7<96, 16, 27, DIM3, false><<<dim3(54, 6), 512, 0, stream>>>(
      BN3_96, WT + WTS[7], 96, R4, 96, 0, nullptr, 0, S(7), L3, CNT + 2);       // b3a
  k_bnapply2<96><<<BNG, 256, 0, stream>>>(R4, 96, 0, S(7), S(7), 96, L3, CNT + 2, BN3_96);
  k_conv7<96, 16, 27, DIM3, false><<<dim3(54, 6), 512, 0, stream>>>(
      BN3_96, WT + WTS[8], 96, X3R, 96, 0, D2R, 96, S(8), L3, CNT + 2);         // x3
  k_bnapply2<96><<<BNG, 256, 0, stream>>>(X3R, 96, 0, S(8), S(8), 96, L3, CNT + 2, BN3_96);
  k_conv7<96, 32, 8, DIM2, true><<<dim3(128, 2), 512, 0, stream>>>(
      BN3_96, WT + WTS[14], 64, CAT2, 128, 64, nullptr, 0, S(9), L2, CNT + 1);  // u2

  // ---- tail level 2 (h2 split into two 64-ci halves) ----
  k_bnapply2<64><<<BNG, 256, 0, stream>>>(CAT2, 128, 64, S(9), S(9), 64, L2, CNT + 1, BN2B);
  k_conv7<64, 32, 27, DIM2, false><<<dim3(128, 2), 512, 0, stream>>>(
      BN2A, WT + WTS[9], 64, R3, 64, 0, nullptr, 0, S(15), L2, CNT + 1);        // h2A (x2 half)
  k_conv7<64, 32, 27, DIM2, false><<<dim3(128, 2), 512, 0, stream>>>(
      BN2B, WT + WTS[10], 64, R3, 64, 0, R3, 64, S(10), L2, CNT + 1);           // h2B (+res)
  k_bnapply2<64><<<BNG, 256, 0, stream>>>(R3, 64, 0, S(10), S(10), 64, L2, CNT + 1, BN2A);
  k_sc<128, 64><<<512, 256, 0, stream>>>(CAT2, (const float*)d_in[12], D1R, L2, CNT + 1);
  k_conv7<64, 32, 27, DIM2, false><<<dim3(128, 2), 512, 0, stream>>>(
      BN2A, WT + WTS[11], 64, R3, 64, 0, D1R, 64, S(11), L2, CNT + 1);          // t2
  k_bnapply2<64><<<BNG, 256, 0, stream>>>(R3, 64, 0, S(11), S(11), 64, L2, CNT + 1, BN2A);
  k_conv7<64, 32, 8, D1, true><<<dim3(256, 1), 512, 0, stream>>>(
      BN2A, WT + WTS[15], 32, CAT1, 64, 32, nullptr, 0, S(12), L1, CNT + 0);    // u1

  // ---- tail level 1 ----
  k_bnapply2<64><<<BNG, 256, 0, stream>>>(CAT1, 64, 0, S(2), S(12), 32, L1, CNT + 0, BN1_64);
  k_conv7<64, 32, 27, D1, false><<<dim3(256, 1), 512, 0, stream>>>(
      BN1_64, WT + WTS[12], 32, R1, 32, 0, nullptr, 0, S(13), L1, CNT + 0);     // h1
  k_bnapply2<32><<<BNG, 256, 0, stream>>>(R1, 32, 0, S(13), S(13), 32, L1, CNT + 0, BN1_32);
  k_sc<64, 32><<<512, 256, 0, stream>>>(CAT1, (const float*)d_in[16], A, L1, CNT + 0);
  k_conv7<32, 32, 27, D1, false><<<dim3(256, 1), 512, 0, stream>>>(
      BN1_32, WT + WTS[13], 32, A, 32, 0, A, 32, S(14), L1, CNT + 0);           // t1
  k_bnout<<<N1 * 8 / 256, 256, 0, stream>>>(A, M1, S(14), CNT + 0, (float*)d_out);
}